// Round 4
// baseline (636.294 us; speedup 1.0000x reference)
//
#include <hip/hip_runtime.h>

// GraphSAGE 3-layer, N=100k E=640k D=128.
// edge_index arrives as int32 (harness converts integer inputs to int32).
// Structure: CSR build (count/scan/fill) once per call; per layer:
//   wave-per-node mean-aggregate (bf16 in, fp32 acc, bf16 out)
//   fused GEMM: out = agg@Wl^T + x@Wr^T + b  via mfma_f32_16x16x32_bf16.

typedef __attribute__((ext_vector_type(8))) short bf16x8;
typedef __attribute__((ext_vector_type(4))) float f32x4;
typedef __attribute__((ext_vector_type(4))) unsigned int u32x4;

__device__ __forceinline__ unsigned short f2bf(float f) {
  unsigned u = __float_as_uint(f);
  u += 0x7fffu + ((u >> 16) & 1u);   // RNE
  return (unsigned short)(u >> 16);
}

// ---------- fp32 -> bf16 convert, 8 elems/thread ----------
__global__ __launch_bounds__(256) void cvt_kernel(const float* __restrict__ in,
                                                  unsigned short* __restrict__ out, int n8) {
  int i = blockIdx.x * 256 + threadIdx.x;
  if (i >= n8) return;
  const float4* p = (const float4*)(in + (size_t)i * 8);
  float4 a = p[0], b = p[1];
  union { unsigned short s[8]; u32x4 u; } pk;
  pk.s[0] = f2bf(a.x); pk.s[1] = f2bf(a.y); pk.s[2] = f2bf(a.z); pk.s[3] = f2bf(a.w);
  pk.s[4] = f2bf(b.x); pk.s[5] = f2bf(b.y); pk.s[6] = f2bf(b.z); pk.s[7] = f2bf(b.w);
  *(u32x4*)(out + (size_t)i * 8) = pk.u;
}

// ---------- CSR build ----------
__global__ __launch_bounds__(256) void count_kernel(const int* __restrict__ dst,
                                                    int* __restrict__ cnt, int E) {
  int e = blockIdx.x * 256 + threadIdx.x;
  if (e < E) atomicAdd(&cnt[dst[e]], 1);
}

__global__ __launch_bounds__(1024) void scan_kernel(const int* __restrict__ cnt,
                                                    int* __restrict__ rowstart, int N) {
  __shared__ int s[1024];
  int t = threadIdx.x;
  int chunk = (N + 1023) >> 10;
  int lo = t * chunk, hi = lo + chunk;
  if (lo > N) lo = N;
  if (hi > N) hi = N;
  int sum = 0;
  for (int i = lo; i < hi; ++i) sum += cnt[i];
  s[t] = sum;
  __syncthreads();
  for (int off = 1; off < 1024; off <<= 1) {
    int v = (t >= off) ? s[t - off] : 0;
    __syncthreads();
    s[t] += v;
    __syncthreads();
  }
  int run = (t == 0) ? 0 : s[t - 1];
  for (int i = lo; i < hi; ++i) { rowstart[i] = run; run += cnt[i]; }
  if (t == 1023) rowstart[N] = run;
}

__global__ __launch_bounds__(256) void init_kernel(const int* __restrict__ rowstart,
                                                   const int* __restrict__ cnt,
                                                   int* __restrict__ cursor,
                                                   float* __restrict__ inv, int N) {
  int n = blockIdx.x * 256 + threadIdx.x;
  if (n < N) {
    cursor[n] = rowstart[n];
    inv[n] = 1.f / fmaxf((float)cnt[n], 1.f);
  }
}

__global__ __launch_bounds__(256) void fill_kernel(const int* __restrict__ src,
                                                   const int* __restrict__ dst,
                                                   int* __restrict__ cursor,
                                                   int* __restrict__ elist, int E) {
  int e = blockIdx.x * 256 + threadIdx.x;
  if (e < E) {
    int d = dst[e];
    int pos = atomicAdd(&cursor[d], 1);
    elist[pos] = src[e];
  }
}

// ---------- mean aggregate: one wave per node ----------
__global__ __launch_bounds__(256) void aggregate_kernel(const unsigned short* __restrict__ xbf,
                                                        const int* __restrict__ rowstart,
                                                        const int* __restrict__ elist,
                                                        const float* __restrict__ inv,
                                                        unsigned short* __restrict__ aggbf, int N) {
  int gid = blockIdx.x * 256 + threadIdx.x;
  int node = gid >> 6, lane = gid & 63;
  if (node >= N) return;
  int beg = rowstart[node], end = rowstart[node + 1];
  float a0 = 0.f, a1 = 0.f;
  for (int e = beg; e < end; ++e) {
    int s = elist[e];
    unsigned u = *(const unsigned*)(xbf + ((size_t)s << 7) + lane * 2);
    a0 += __uint_as_float(u << 16);
    a1 += __uint_as_float(u & 0xffff0000u);
  }
  float iv = inv[node];
  a0 *= iv; a1 *= iv;
  unsigned o = ((unsigned)f2bf(a1) << 16) | (unsigned)f2bf(a0);
  *(unsigned*)(aggbf + ((size_t)node << 7) + lane * 2) = o;
}

// ---------- fused SAGE GEMM: out = Abf@Wl^T + Xbf@Wr^T + b ----------
// block = 256 thr (4 waves), tile = 256 rows x 128 cols; wave w owns 64 rows.
// Wl/Wr staged to LDS as bf16, 16B chunks XOR-swizzled by (o&15) to kill the
// o*256B-stride bank conflict on ds_read_b128.
__global__ __launch_bounds__(256, 2) void sage_gemm(
    const unsigned short* __restrict__ Abf, const unsigned short* __restrict__ Xbf,
    const float* __restrict__ Wl, const float* __restrict__ Wr, const float* __restrict__ bias,
    float* __restrict__ outf, unsigned short* __restrict__ outb, int N, int relu) {
  __shared__ __align__(16) unsigned short sW[2][128][128];  // 64 KB
  const int tid = threadIdx.x;
  for (int it = tid; it < 4096; it += 256) {
    int m = it >> 11;
    int o = (it >> 4) & 127;
    int ch = it & 15;
    const float* wsrc = (m ? Wr : Wl) + o * 128 + ch * 8;
    float4 f0 = *(const float4*)wsrc;
    float4 f1 = *(const float4*)(wsrc + 4);
    union { unsigned short s[8]; u32x4 u; } pk;
    pk.s[0] = f2bf(f0.x); pk.s[1] = f2bf(f0.y); pk.s[2] = f2bf(f0.z); pk.s[3] = f2bf(f0.w);
    pk.s[4] = f2bf(f1.x); pk.s[5] = f2bf(f1.y); pk.s[6] = f2bf(f1.z); pk.s[7] = f2bf(f1.w);
    *(u32x4*)&sW[m][o][(ch ^ (o & 15)) << 3] = pk.u;
  }
  __syncthreads();

  const int l = tid & 63;
  const int w = tid >> 6;
  const int l15 = l & 15;
  const int lg = l >> 4;
  const int row_base = blockIdx.x * 256 + w * 64;

  f32x4 acc[4][8];
#pragma unroll
  for (int rt = 0; rt < 4; ++rt)
#pragma unroll
    for (int ot = 0; ot < 8; ++ot) acc[rt][ot] = f32x4{0.f, 0.f, 0.f, 0.f};

  union frag { u32x4 u; bf16x8 v; };

  int rrow[4];
#pragma unroll
  for (int rt = 0; rt < 4; ++rt) {
    int r = row_base + rt * 16 + l15;
    rrow[rt] = (r < N) ? r : (N - 1);
  }

#pragma unroll
  for (int h = 0; h < 2; ++h) {
    const unsigned short* Asrc = h ? Xbf : Abf;
#pragma unroll
    for (int ks = 0; ks < 4; ++ks) {
      frag af[4];
#pragma unroll
      for (int rt = 0; rt < 4; ++rt)
        af[rt].u = *(const u32x4*)(Asrc + ((size_t)rrow[rt] << 7) + (ks * 32 + lg * 8));
      frag bq[8];
#pragma unroll
      for (int ot = 0; ot < 8; ++ot)
        bq[ot].u = *(const u32x4*)&sW[h][ot * 16 + l15][((((ks << 2) | lg) ^ l15)) << 3];
#pragma unroll
      for (int rt = 0; rt < 4; ++rt)
#pragma unroll
        for (int ot = 0; ot < 8; ++ot)
          acc[rt][ot] = __builtin_amdgcn_mfma_f32_16x16x32_bf16(af[rt].v, bq[ot].v, acc[rt][ot], 0, 0, 0);
    }
  }

  float bv[8];
#pragma unroll
  for (int ot = 0; ot < 8; ++ot) bv[ot] = bias[ot * 16 + l15];

#pragma unroll
  for (int rt = 0; rt < 4; ++rt) {
#pragma unroll
    for (int i = 0; i < 4; ++i) {
      int r = row_base + rt * 16 + lg * 4 + i;
      if (r < N) {
#pragma unroll
        for (int ot = 0; ot < 8; ++ot) {
          float v = acc[rt][ot][i] + bv[ot];
          if (relu) v = fmaxf(v, 0.f);
          size_t idx = ((size_t)r << 7) + ot * 16 + l15;
          if (outf) outf[idx] = v;
          else outb[idx] = f2bf(v);
        }
      }
    }
  }
}

extern "C" void kernel_launch(void* const* d_in, const int* in_sizes, int n_in,
                              void* d_out, int out_size, void* d_ws, size_t ws_size,
                              hipStream_t stream) {
  (void)n_in; (void)out_size; (void)ws_size;
  const float* x = (const float*)d_in[0];
  const int* ei = (const int*)d_in[1];     // int64 in reference -> int32 from harness
  const float* W1l = (const float*)d_in[2];
  const float* b1 = (const float*)d_in[3];
  const float* W1r = (const float*)d_in[4];
  const float* W2l = (const float*)d_in[5];
  const float* b2 = (const float*)d_in[6];
  const float* W2r = (const float*)d_in[7];
  const float* W3l = (const float*)d_in[8];
  const float* b3 = (const float*)d_in[9];
  const float* W3r = (const float*)d_in[10];
  float* out = (float*)d_out;

  const int N = in_sizes[0] / 128;
  const int E = in_sizes[1] / 2;
  const int* srcp = ei;
  const int* dstp = ei + E;

  char* ws = (char*)d_ws;
  size_t off = 0;
  auto alloc = [&](size_t bytes) {
    void* p = ws + off;
    off = (off + bytes + 255) & ~(size_t)255;
    return p;
  };
  // Ping-pong node-feature buffers: bufA holds x (then layer-2 output), bufB holds layer-1 output.
  unsigned short* bufA = (unsigned short*)alloc((size_t)N * 128 * 2);
  unsigned short* bufB = (unsigned short*)alloc((size_t)N * 128 * 2);
  unsigned short* aggbf = (unsigned short*)alloc((size_t)N * 128 * 2);
  int* cnt = (int*)alloc((size_t)N * 4);
  int* rowstart = (int*)alloc((size_t)(N + 1) * 4);
  int* cursor = (int*)alloc((size_t)N * 4);
  float* inv = (float*)alloc((size_t)N * 4);
  int* elist = (int*)alloc((size_t)E * 4);

  hipMemsetAsync(cnt, 0, (size_t)N * 4, stream);
  cvt_kernel<<<(N * 128 / 8 + 255) / 256, 256, 0, stream>>>(x, bufA, N * 128 / 8);
  count_kernel<<<(E + 255) / 256, 256, 0, stream>>>(dstp, cnt, E);
  scan_kernel<<<1, 1024, 0, stream>>>(cnt, rowstart, N);
  init_kernel<<<(N + 255) / 256, 256, 0, stream>>>(rowstart, cnt, cursor, inv, N);
  fill_kernel<<<(E + 255) / 256, 256, 0, stream>>>(srcp, dstp, cursor, elist, E);

  int aggBlocks = (N + 3) / 4;
  int gemmBlocks = (N + 255) / 256;

  // layer 1: bufA(x) -> bufB (relu)
  aggregate_kernel<<<aggBlocks, 256, 0, stream>>>(bufA, rowstart, elist, inv, aggbf, N);
  sage_gemm<<<gemmBlocks, 256, 0, stream>>>(aggbf, bufA, W1l, W1r, b1, nullptr, bufB, N, 1);
  // layer 2: bufB -> bufA (relu; x dead, safe to overwrite)
  aggregate_kernel<<<aggBlocks, 256, 0, stream>>>(bufB, rowstart, elist, inv, aggbf, N);
  sage_gemm<<<gemmBlocks, 256, 0, stream>>>(aggbf, bufB, W2l, W2r, b2, nullptr, bufA, N, 1);
  // layer 3: bufA -> out (no relu, fp32)
  aggregate_kernel<<<aggBlocks, 256, 0, stream>>>(bufA, rowstart, elist, inv, aggbf, N);
  sage_gemm<<<gemmBlocks, 256, 0, stream>>>(aggbf, bufA, W3l, W3r, b3, out, nullptr, N, 0);
}

// Round 6
// 485.225 us; speedup vs baseline: 1.3113x; 1.3113x over previous
//
#include <hip/hip_runtime.h>

// GraphSAGE 3-layer, N=100k E=640k D=128.
// edge_index arrives as int32 (harness converts integer inputs to int32).
// CSR build: count -> hierarchical scan (partial/mid/final) -> fill. Per layer:
//   wave-per-node mean-aggregate (bf16 in, fp32 acc, bf16 out)
//   fused GEMM: out = agg@Wl^T + x@Wr^T + b  via mfma_f32_16x16x32_bf16.

typedef __attribute__((ext_vector_type(8))) short bf16x8;
typedef __attribute__((ext_vector_type(4))) float f32x4;
typedef __attribute__((ext_vector_type(4))) unsigned int u32x4;

__device__ __forceinline__ unsigned short f2bf(float f) {
  unsigned u = __float_as_uint(f);
  u += 0x7fffu + ((u >> 16) & 1u);   // RNE
  return (unsigned short)(u >> 16);
}

// ---------- fp32 -> bf16 convert, 8 elems/thread ----------
__global__ __launch_bounds__(256) void cvt_kernel(const float* __restrict__ in,
                                                  unsigned short* __restrict__ out, int n8) {
  int i = blockIdx.x * 256 + threadIdx.x;
  if (i >= n8) return;
  const float4* p = (const float4*)(in + (size_t)i * 8);
  float4 a = p[0], b = p[1];
  union { unsigned short s[8]; u32x4 u; } pk;
  pk.s[0] = f2bf(a.x); pk.s[1] = f2bf(a.y); pk.s[2] = f2bf(a.z); pk.s[3] = f2bf(a.w);
  pk.s[4] = f2bf(b.x); pk.s[5] = f2bf(b.y); pk.s[6] = f2bf(b.z); pk.s[7] = f2bf(b.w);
  *(u32x4*)(out + (size_t)i * 8) = pk.u;
}

// ---------- CSR build ----------
__global__ __launch_bounds__(256) void count_kernel(const int* __restrict__ dst,
                                                    int* __restrict__ cnt, int E) {
  int e = blockIdx.x * 256 + threadIdx.x;
  if (e < E) atomicAdd(&cnt[dst[e]], 1);
}

// 2048 counts per block -> blocksum[b]
__global__ __launch_bounds__(256) void partial_kernel(const int* __restrict__ cnt,
                                                      int* __restrict__ blocksum, int N) {
  __shared__ int red[256];
  int t = threadIdx.x;
  int idx = blockIdx.x * 2048 + t * 8;
  int s = 0;
  if (idx + 8 <= N) {
    int4 a = *(const int4*)(cnt + idx);
    int4 b = *(const int4*)(cnt + idx + 4);
    s = a.x + a.y + a.z + a.w + b.x + b.y + b.z + b.w;
  } else {
    for (int i = idx; i < N && i < idx + 8; ++i) s += cnt[i];
  }
  red[t] = s;
  __syncthreads();
  for (int off = 128; off > 0; off >>= 1) {
    if (t < off) red[t] += red[t + off];
    __syncthreads();
  }
  if (t == 0) blocksum[blockIdx.x] = red[0];
}

// single wave scans <=64 block partials -> exclusive blockoff[b]
__global__ __launch_bounds__(64) void scanmid_kernel(const int* __restrict__ blocksum,
                                                     int* __restrict__ blockoff, int nb) {
  int l = threadIdx.x;
  int own = (l < nb) ? blocksum[l] : 0;
  int v = own;
  for (int off = 1; off < 64; off <<= 1) {
    int u = __shfl_up(v, off);
    if (l >= off) v += u;
  }
  if (l < nb) blockoff[l] = v - own;
}

// local scan of 2048 counts + write rowstart/cursor/inv (init fused here)
__global__ __launch_bounds__(256) void final_kernel(const int* __restrict__ cnt,
                                                    const int* __restrict__ blockoff,
                                                    int* __restrict__ rowstart,
                                                    int* __restrict__ cursor,
                                                    float* __restrict__ inv, int N) {
  __shared__ int thr[256];
  int t = threadIdx.x;
  int idx = blockIdx.x * 2048 + t * 8;
  int c[8];
  int s = 0;
#pragma unroll
  for (int i = 0; i < 8; ++i) {
    int n = idx + i;
    c[i] = (n < N) ? cnt[n] : 0;
    s += c[i];
  }
  thr[t] = s;
  __syncthreads();
  for (int off = 1; off < 256; off <<= 1) {
    int u = (t >= off) ? thr[t - off] : 0;
    __syncthreads();
    thr[t] += u;
    __syncthreads();
  }
  int run = blockoff[blockIdx.x] + thr[t] - s;  // exclusive prefix for this thread
#pragma unroll
  for (int i = 0; i < 8; ++i) {
    int n = idx + i;
    if (n < N) {
      rowstart[n] = run;
      cursor[n] = run;
      inv[n] = 1.f / fmaxf((float)c[i], 1.f);
      run += c[i];
      if (n == N - 1) rowstart[N] = run;
    }
  }
}

__global__ __launch_bounds__(256) void fill_kernel(const int* __restrict__ src,
                                                   const int* __restrict__ dst,
                                                   int* __restrict__ cursor,
                                                   int* __restrict__ elist, int E) {
  int e = blockIdx.x * 256 + threadIdx.x;
  if (e < E) {
    int d = dst[e];
    int pos = atomicAdd(&cursor[d], 1);
    elist[pos] = src[e];
  }
}

// ---------- mean aggregate: one wave per node ----------
__global__ __launch_bounds__(256) void aggregate_kernel(const unsigned short* __restrict__ xbf,
                                                        const int* __restrict__ rowstart,
                                                        const int* __restrict__ elist,
                                                        const float* __restrict__ inv,
                                                        unsigned short* __restrict__ aggbf, int N) {
  int gid = blockIdx.x * 256 + threadIdx.x;
  int node = gid >> 6, lane = gid & 63;
  if (node >= N) return;
  int beg = rowstart[node], end = rowstart[node + 1];
  float a0 = 0.f, a1 = 0.f;
  for (int e = beg; e < end; ++e) {
    int s = elist[e];
    unsigned u = *(const unsigned*)(xbf + ((size_t)s << 7) + lane * 2);
    a0 += __uint_as_float(u << 16);
    a1 += __uint_as_float(u & 0xffff0000u);
  }
  float iv = inv[node];
  a0 *= iv; a1 *= iv;
  unsigned o = ((unsigned)f2bf(a1) << 16) | (unsigned)f2bf(a0);
  *(unsigned*)(aggbf + ((size_t)node << 7) + lane * 2) = o;
}

// ---------- fused SAGE GEMM: out = Abf@Wl^T + Xbf@Wr^T + b ----------
// block = 256 thr (4 waves), tile = 256 rows x 128 cols; wave w owns 64 rows.
// Wl/Wr staged to LDS as bf16, 16B chunks XOR-swizzled by (o&15) to kill the
// o*256B-stride bank conflict on ds_read_b128.
__global__ __launch_bounds__(256, 2) void sage_gemm(
    const unsigned short* __restrict__ Abf, const unsigned short* __restrict__ Xbf,
    const float* __restrict__ Wl, const float* __restrict__ Wr, const float* __restrict__ bias,
    float* __restrict__ outf, unsigned short* __restrict__ outb, int N, int relu) {
  __shared__ __align__(16) unsigned short sW[2][128][128];  // 64 KB
  const int tid = threadIdx.x;
  for (int it = tid; it < 4096; it += 256) {
    int m = it >> 11;
    int o = (it >> 4) & 127;
    int ch = it & 15;
    const float* wsrc = (m ? Wr : Wl) + o * 128 + ch * 8;
    float4 f0 = *(const float4*)wsrc;
    float4 f1 = *(const float4*)(wsrc + 4);
    union { unsigned short s[8]; u32x4 u; } pk;
    pk.s[0] = f2bf(f0.x); pk.s[1] = f2bf(f0.y); pk.s[2] = f2bf(f0.z); pk.s[3] = f2bf(f0.w);
    pk.s[4] = f2bf(f1.x); pk.s[5] = f2bf(f1.y); pk.s[6] = f2bf(f1.z); pk.s[7] = f2bf(f1.w);
    *(u32x4*)&sW[m][o][(ch ^ (o & 15)) << 3] = pk.u;
  }
  __syncthreads();

  const int l = tid & 63;
  const int w = tid >> 6;
  const int l15 = l & 15;
  const int lg = l >> 4;
  const int row_base = blockIdx.x * 256 + w * 64;

  f32x4 acc[4][8];
#pragma unroll
  for (int rt = 0; rt < 4; ++rt)
#pragma unroll
    for (int ot = 0; ot < 8; ++ot) acc[rt][ot] = f32x4{0.f, 0.f, 0.f, 0.f};

  union frag { u32x4 u; bf16x8 v; };

  int rrow[4];
#pragma unroll
  for (int rt = 0; rt < 4; ++rt) {
    int r = row_base + rt * 16 + l15;
    rrow[rt] = (r < N) ? r : (N - 1);
  }

#pragma unroll
  for (int h = 0; h < 2; ++h) {
    const unsigned short* Asrc = h ? Xbf : Abf;
#pragma unroll
    for (int ks = 0; ks < 4; ++ks) {
      frag af[4];
#pragma unroll
      for (int rt = 0; rt < 4; ++rt)
        af[rt].u = *(const u32x4*)(Asrc + ((size_t)rrow[rt] << 7) + (ks * 32 + lg * 8));
      frag bq[8];
#pragma unroll
      for (int ot = 0; ot < 8; ++ot)
        bq[ot].u = *(const u32x4*)&sW[h][ot * 16 + l15][((((ks << 2) | lg) ^ l15)) << 3];
#pragma unroll
      for (int rt = 0; rt < 4; ++rt)
#pragma unroll
        for (int ot = 0; ot < 8; ++ot)
          acc[rt][ot] = __builtin_amdgcn_mfma_f32_16x16x32_bf16(af[rt].v, bq[ot].v, acc[rt][ot], 0, 0, 0);
    }
  }

  float bv[8];
#pragma unroll
  for (int ot = 0; ot < 8; ++ot) bv[ot] = bias[ot * 16 + l15];

#pragma unroll
  for (int rt = 0; rt < 4; ++rt) {
#pragma unroll
    for (int i = 0; i < 4; ++i) {
      int r = row_base + rt * 16 + lg * 4 + i;
      if (r < N) {
#pragma unroll
        for (int ot = 0; ot < 8; ++ot) {
          float v = acc[rt][ot][i] + bv[ot];
          if (relu) v = fmaxf(v, 0.f);
          size_t idx = ((size_t)r << 7) + ot * 16 + l15;
          if (outf) outf[idx] = v;
          else outb[idx] = f2bf(v);
        }
      }
    }
  }
}

extern "C" void kernel_launch(void* const* d_in, const int* in_sizes, int n_in,
                              void* d_out, int out_size, void* d_ws, size_t ws_size,
                              hipStream_t stream) {
  (void)n_in; (void)out_size; (void)ws_size;
  const float* x = (const float*)d_in[0];
  const int* ei = (const int*)d_in[1];     // int64 in reference -> int32 from harness
  const float* W1l = (const float*)d_in[2];
  const float* b1 = (const float*)d_in[3];
  const float* W1r = (const float*)d_in[4];
  const float* W2l = (const float*)d_in[5];
  const float* b2 = (const float*)d_in[6];
  const float* W2r = (const float*)d_in[7];
  const float* W3l = (const float*)d_in[8];
  const float* b3 = (const float*)d_in[9];
  const float* W3r = (const float*)d_in[10];
  float* out = (float*)d_out;

  const int N = in_sizes[0] / 128;
  const int E = in_sizes[1] / 2;
  const int* srcp = ei;
  const int* dstp = ei + E;

  char* ws = (char*)d_ws;
  size_t off = 0;
  auto alloc = [&](size_t bytes) {
    void* p = ws + off;
    off = (off + bytes + 255) & ~(size_t)255;
    return p;
  };
  // Ping-pong node-feature buffers: bufA holds x (then layer-2 output), bufB holds layer-1 output.
  unsigned short* bufA = (unsigned short*)alloc((size_t)N * 128 * 2);
  unsigned short* bufB = (unsigned short*)alloc((size_t)N * 128 * 2);
  unsigned short* aggbf = (unsigned short*)alloc((size_t)N * 128 * 2);
  int* cnt = (int*)alloc((size_t)N * 4);
  int* rowstart = (int*)alloc((size_t)(N + 1) * 4);
  int* cursor = (int*)alloc((size_t)N * 4);
  float* inv = (float*)alloc((size_t)N * 4);
  int* elist = (int*)alloc((size_t)E * 4);
  int* blocksum = (int*)alloc(64 * 4);
  int* blockoff = (int*)alloc(64 * 4);

  const int nb = (N + 2047) / 2048;  // 49 for N=100k (<=64 by construction here)

  hipMemsetAsync(cnt, 0, (size_t)N * 4, stream);
  cvt_kernel<<<(N * 128 / 8 + 255) / 256, 256, 0, stream>>>(x, bufA, N * 128 / 8);
  count_kernel<<<(E + 255) / 256, 256, 0, stream>>>(dstp, cnt, E);
  partial_kernel<<<nb, 256, 0, stream>>>(cnt, blocksum, N);
  scanmid_kernel<<<1, 64, 0, stream>>>(blocksum, blockoff, nb);
  final_kernel<<<nb, 256, 0, stream>>>(cnt, blockoff, rowstart, cursor, inv, N);
  fill_kernel<<<(E + 255) / 256, 256, 0, stream>>>(srcp, dstp, cursor, elist, E);

  int aggBlocks = (N + 3) / 4;
  int gemmBlocks = (N + 255) / 256;

  // layer 1: bufA(x) -> bufB (relu)
  aggregate_kernel<<<aggBlocks, 256, 0, stream>>>(bufA, rowstart, elist, inv, aggbf, N);
  sage_gemm<<<gemmBlocks, 256, 0, stream>>>(aggbf, bufA, W1l, W1r, b1, nullptr, bufB, N, 1);
  // layer 2: bufB -> bufA (relu; x dead, safe to overwrite)
  aggregate_kernel<<<aggBlocks, 256, 0, stream>>>(bufB, rowstart, elist, inv, aggbf, N);
  sage_gemm<<<gemmBlocks, 256, 0, stream>>>(aggbf, bufB, W2l, W2r, b2, nullptr, bufA, N, 1);
  // layer 3: bufA -> out (no relu, fp32)
  aggregate_kernel<<<aggBlocks, 256, 0, stream>>>(bufA, rowstart, elist, inv, aggbf, N);
  sage_gemm<<<gemmBlocks, 256, 0, stream>>>(aggbf, bufA, W3l, W3r, b3, out, nullptr, N, 0);
}

// Round 7
// 396.606 us; speedup vs baseline: 1.6043x; 1.2234x over previous
//
#include <hip/hip_runtime.h>

// GraphSAGE 3-layer, N=100k E=640k D=128.
// edge_index arrives as int32 (harness converts integer inputs to int32).
// CSR build: count -> hierarchical scan (partial/mid/final) -> fill. Per layer:
//   mean-aggregate: 4x16-lane groups per wave, one node per wave, dwordx4 rows
//   fused GEMM: out = agg@Wl^T + x@Wr^T + b  via mfma_f32_16x16x32_bf16.

typedef __attribute__((ext_vector_type(8))) short bf16x8;
typedef __attribute__((ext_vector_type(4))) float f32x4;
typedef __attribute__((ext_vector_type(4))) unsigned int u32x4;

__device__ __forceinline__ unsigned short f2bf(float f) {
  unsigned u = __float_as_uint(f);
  u += 0x7fffu + ((u >> 16) & 1u);   // RNE
  return (unsigned short)(u >> 16);
}

// ---------- fp32 -> bf16 convert, 8 elems/thread ----------
__global__ __launch_bounds__(256) void cvt_kernel(const float* __restrict__ in,
                                                  unsigned short* __restrict__ out, int n8) {
  int i = blockIdx.x * 256 + threadIdx.x;
  if (i >= n8) return;
  const float4* p = (const float4*)(in + (size_t)i * 8);
  float4 a = p[0], b = p[1];
  union { unsigned short s[8]; u32x4 u; } pk;
  pk.s[0] = f2bf(a.x); pk.s[1] = f2bf(a.y); pk.s[2] = f2bf(a.z); pk.s[3] = f2bf(a.w);
  pk.s[4] = f2bf(b.x); pk.s[5] = f2bf(b.y); pk.s[6] = f2bf(b.z); pk.s[7] = f2bf(b.w);
  *(u32x4*)(out + (size_t)i * 8) = pk.u;
}

// ---------- CSR build ----------
__global__ __launch_bounds__(256) void count_kernel(const int* __restrict__ dst,
                                                    int* __restrict__ cnt, int E) {
  int e = blockIdx.x * 256 + threadIdx.x;
  if (e < E) atomicAdd(&cnt[dst[e]], 1);
}

// 2048 counts per block -> blocksum[b]
__global__ __launch_bounds__(256) void partial_kernel(const int* __restrict__ cnt,
                                                      int* __restrict__ blocksum, int N) {
  __shared__ int red[256];
  int t = threadIdx.x;
  int idx = blockIdx.x * 2048 + t * 8;
  int s = 0;
  if (idx + 8 <= N) {
    int4 a = *(const int4*)(cnt + idx);
    int4 b = *(const int4*)(cnt + idx + 4);
    s = a.x + a.y + a.z + a.w + b.x + b.y + b.z + b.w;
  } else {
    for (int i = idx; i < N && i < idx + 8; ++i) s += cnt[i];
  }
  red[t] = s;
  __syncthreads();
  for (int off = 128; off > 0; off >>= 1) {
    if (t < off) red[t] += red[t + off];
    __syncthreads();
  }
  if (t == 0) blocksum[blockIdx.x] = red[0];
}

// single wave scans <=64 block partials -> exclusive blockoff[b]
__global__ __launch_bounds__(64) void scanmid_kernel(const int* __restrict__ blocksum,
                                                     int* __restrict__ blockoff, int nb) {
  int l = threadIdx.x;
  int own = (l < nb) ? blocksum[l] : 0;
  int v = own;
  for (int off = 1; off < 64; off <<= 1) {
    int u = __shfl_up(v, off);
    if (l >= off) v += u;
  }
  if (l < nb) blockoff[l] = v - own;
}

// local scan of 2048 counts + write rowstart/cursor/inv (init fused here)
__global__ __launch_bounds__(256) void final_kernel(const int* __restrict__ cnt,
                                                    const int* __restrict__ blockoff,
                                                    int* __restrict__ rowstart,
                                                    int* __restrict__ cursor,
                                                    float* __restrict__ inv, int N) {
  __shared__ int thr[256];
  int t = threadIdx.x;
  int idx = blockIdx.x * 2048 + t * 8;
  int c[8];
  int s = 0;
#pragma unroll
  for (int i = 0; i < 8; ++i) {
    int n = idx + i;
    c[i] = (n < N) ? cnt[n] : 0;
    s += c[i];
  }
  thr[t] = s;
  __syncthreads();
  for (int off = 1; off < 256; off <<= 1) {
    int u = (t >= off) ? thr[t - off] : 0;
    __syncthreads();
    thr[t] += u;
    __syncthreads();
  }
  int run = blockoff[blockIdx.x] + thr[t] - s;  // exclusive prefix for this thread
#pragma unroll
  for (int i = 0; i < 8; ++i) {
    int n = idx + i;
    if (n < N) {
      rowstart[n] = run;
      cursor[n] = run;
      inv[n] = 1.f / fmaxf((float)c[i], 1.f);
      run += c[i];
      if (n == N - 1) rowstart[N] = run;
    }
  }
}

__global__ __launch_bounds__(256) void fill_kernel(const int* __restrict__ src,
                                                   const int* __restrict__ dst,
                                                   int* __restrict__ cursor,
                                                   int* __restrict__ elist, int E) {
  int e = blockIdx.x * 256 + threadIdx.x;
  if (e < E) {
    int d = dst[e];
    int pos = atomicAdd(&cursor[d], 1);
    elist[pos] = src[e];
  }
}

// ---------- mean aggregate: one node per wave, 4x16-lane groups ----------
// Group g handles edges beg+g, beg+g+4, ...; lane covers 8 cols via dwordx4.
// 4 independent row-gathers in flight per wave (vs 1 in the naive loop).
__global__ __launch_bounds__(256) void aggregate_kernel(const unsigned short* __restrict__ xbf,
                                                        const int* __restrict__ rowstart,
                                                        const int* __restrict__ elist,
                                                        const float* __restrict__ inv,
                                                        unsigned short* __restrict__ aggbf, int N) {
  int gid = blockIdx.x * 256 + threadIdx.x;
  int node = gid >> 6;
  if (node >= N) return;
  int lane = threadIdx.x & 63;
  int grp = lane >> 4;    // 0..3
  int l16 = lane & 15;    // 0..15

  int beg = rowstart[node], end = rowstart[node + 1];
  float acc[8];
#pragma unroll
  for (int j = 0; j < 8; ++j) acc[j] = 0.f;

  for (int e = beg + grp; e < end; e += 4) {
    int s = elist[e];
    u32x4 u = *(const u32x4*)(xbf + ((size_t)s << 7) + l16 * 8);
#pragma unroll
    for (int d = 0; d < 4; ++d) {
      acc[2 * d]     += __uint_as_float(u[d] << 16);
      acc[2 * d + 1] += __uint_as_float(u[d] & 0xffff0000u);
    }
  }

  // combine the 4 groups' partials: lanes {l16, l16+16, l16+32, l16+48}
#pragma unroll
  for (int j = 0; j < 8; ++j) {
    acc[j] += __shfl_xor(acc[j], 16);
    acc[j] += __shfl_xor(acc[j], 32);
  }

  if (grp == 0) {
    float iv = inv[node];
    union { unsigned short s[8]; u32x4 u; } pk;
#pragma unroll
    for (int j = 0; j < 8; ++j) pk.s[j] = f2bf(acc[j] * iv);
    *(u32x4*)(aggbf + ((size_t)node << 7) + l16 * 8) = pk.u;
  }
}

// ---------- fused SAGE GEMM: out = Abf@Wl^T + Xbf@Wr^T + b ----------
// block = 256 thr (4 waves), tile = 256 rows x 128 cols; wave w owns 64 rows.
// Wl/Wr staged to LDS as bf16, 16B chunks XOR-swizzled by (o&15) to kill the
// o*256B-stride bank conflict on ds_read_b128.
__global__ __launch_bounds__(256, 2) void sage_gemm(
    const unsigned short* __restrict__ Abf, const unsigned short* __restrict__ Xbf,
    const float* __restrict__ Wl, const float* __restrict__ Wr, const float* __restrict__ bias,
    float* __restrict__ outf, unsigned short* __restrict__ outb, int N, int relu) {
  __shared__ __align__(16) unsigned short sW[2][128][128];  // 64 KB
  const int tid = threadIdx.x;
  for (int it = tid; it < 4096; it += 256) {
    int m = it >> 11;
    int o = (it >> 4) & 127;
    int ch = it & 15;
    const float* wsrc = (m ? Wr : Wl) + o * 128 + ch * 8;
    float4 f0 = *(const float4*)wsrc;
    float4 f1 = *(const float4*)(wsrc + 4);
    union { unsigned short s[8]; u32x4 u; } pk;
    pk.s[0] = f2bf(f0.x); pk.s[1] = f2bf(f0.y); pk.s[2] = f2bf(f0.z); pk.s[3] = f2bf(f0.w);
    pk.s[4] = f2bf(f1.x); pk.s[5] = f2bf(f1.y); pk.s[6] = f2bf(f1.z); pk.s[7] = f2bf(f1.w);
    *(u32x4*)&sW[m][o][(ch ^ (o & 15)) << 3] = pk.u;
  }
  __syncthreads();

  const int l = tid & 63;
  const int w = tid >> 6;
  const int l15 = l & 15;
  const int lg = l >> 4;
  const int row_base = blockIdx.x * 256 + w * 64;

  f32x4 acc[4][8];
#pragma unroll
  for (int rt = 0; rt < 4; ++rt)
#pragma unroll
    for (int ot = 0; ot < 8; ++ot) acc[rt][ot] = f32x4{0.f, 0.f, 0.f, 0.f};

  union frag { u32x4 u; bf16x8 v; };

  int rrow[4];
#pragma unroll
  for (int rt = 0; rt < 4; ++rt) {
    int r = row_base + rt * 16 + l15;
    rrow[rt] = (r < N) ? r : (N - 1);
  }

#pragma unroll
  for (int h = 0; h < 2; ++h) {
    const unsigned short* Asrc = h ? Xbf : Abf;
#pragma unroll
    for (int ks = 0; ks < 4; ++ks) {
      frag af[4];
#pragma unroll
      for (int rt = 0; rt < 4; ++rt)
        af[rt].u = *(const u32x4*)(Asrc + ((size_t)rrow[rt] << 7) + (ks * 32 + lg * 8));
      frag bq[8];
#pragma unroll
      for (int ot = 0; ot < 8; ++ot)
        bq[ot].u = *(const u32x4*)&sW[h][ot * 16 + l15][((((ks << 2) | lg) ^ l15)) << 3];
#pragma unroll
      for (int rt = 0; rt < 4; ++rt)
#pragma unroll
        for (int ot = 0; ot < 8; ++ot)
          acc[rt][ot] = __builtin_amdgcn_mfma_f32_16x16x32_bf16(af[rt].v, bq[ot].v, acc[rt][ot], 0, 0, 0);
    }
  }

  float bv[8];
#pragma unroll
  for (int ot = 0; ot < 8; ++ot) bv[ot] = bias[ot * 16 + l15];

#pragma unroll
  for (int rt = 0; rt < 4; ++rt) {
#pragma unroll
    for (int i = 0; i < 4; ++i) {
      int r = row_base + rt * 16 + lg * 4 + i;
      if (r < N) {
#pragma unroll
        for (int ot = 0; ot < 8; ++ot) {
          float v = acc[rt][ot][i] + bv[ot];
          if (relu) v = fmaxf(v, 0.f);
          size_t idx = ((size_t)r << 7) + ot * 16 + l15;
          if (outf) outf[idx] = v;
          else outb[idx] = f2bf(v);
        }
      }
    }
  }
}

extern "C" void kernel_launch(void* const* d_in, const int* in_sizes, int n_in,
                              void* d_out, int out_size, void* d_ws, size_t ws_size,
                              hipStream_t stream) {
  (void)n_in; (void)out_size; (void)ws_size;
  const float* x = (const float*)d_in[0];
  const int* ei = (const int*)d_in[1];     // int64 in reference -> int32 from harness
  const float* W1l = (const float*)d_in[2];
  const float* b1 = (const float*)d_in[3];
  const float* W1r = (const float*)d_in[4];
  const float* W2l = (const float*)d_in[5];
  const float* b2 = (const float*)d_in[6];
  const float* W2r = (const float*)d_in[7];
  const float* W3l = (const float*)d_in[8];
  const float* b3 = (const float*)d_in[9];
  const float* W3r = (const float*)d_in[10];
  float* out = (float*)d_out;

  const int N = in_sizes[0] / 128;
  const int E = in_sizes[1] / 2;
  const int* srcp = ei;
  const int* dstp = ei + E;

  char* ws = (char*)d_ws;
  size_t off = 0;
  auto alloc = [&](size_t bytes) {
    void* p = ws + off;
    off = (off + bytes + 255) & ~(size_t)255;
    return p;
  };
  // Ping-pong node-feature buffers: bufA holds x (then layer-2 output), bufB holds layer-1 output.
  unsigned short* bufA = (unsigned short*)alloc((size_t)N * 128 * 2);
  unsigned short* bufB = (unsigned short*)alloc((size_t)N * 128 * 2);
  unsigned short* aggbf = (unsigned short*)alloc((size_t)N * 128 * 2);
  int* cnt = (int*)alloc((size_t)N * 4);
  int* rowstart = (int*)alloc((size_t)(N + 1) * 4);
  int* cursor = (int*)alloc((size_t)N * 4);
  float* inv = (float*)alloc((size_t)N * 4);
  int* elist = (int*)alloc((size_t)E * 4);
  int* blocksum = (int*)alloc(64 * 4);
  int* blockoff = (int*)alloc(64 * 4);

  const int nb = (N + 2047) / 2048;  // 49 for N=100k (<=64 by construction here)

  hipMemsetAsync(cnt, 0, (size_t)N * 4, stream);
  cvt_kernel<<<(N * 128 / 8 + 255) / 256, 256, 0, stream>>>(x, bufA, N * 128 / 8);
  count_kernel<<<(E + 255) / 256, 256, 0, stream>>>(dstp, cnt, E);
  partial_kernel<<<nb, 256, 0, stream>>>(cnt, blocksum, N);
  scanmid_kernel<<<1, 64, 0, stream>>>(blocksum, blockoff, nb);
  final_kernel<<<nb, 256, 0, stream>>>(cnt, blockoff, rowstart, cursor, inv, N);
  fill_kernel<<<(E + 255) / 256, 256, 0, stream>>>(srcp, dstp, cursor, elist, E);

  int aggBlocks = (N + 3) / 4;
  int gemmBlocks = (N + 255) / 256;

  // layer 1: bufA(x) -> bufB (relu)
  aggregate_kernel<<<aggBlocks, 256, 0, stream>>>(bufA, rowstart, elist, inv, aggbf, N);
  sage_gemm<<<gemmBlocks, 256, 0, stream>>>(aggbf, bufA, W1l, W1r, b1, nullptr, bufB, N, 1);
  // layer 2: bufB -> bufA (relu; x dead, safe to overwrite)
  aggregate_kernel<<<aggBlocks, 256, 0, stream>>>(bufB, rowstart, elist, inv, aggbf, N);
  sage_gemm<<<gemmBlocks, 256, 0, stream>>>(aggbf, bufB, W2l, W2r, b2, nullptr, bufA, N, 1);
  // layer 3: bufA -> out (no relu, fp32)
  aggregate_kernel<<<aggBlocks, 256, 0, stream>>>(bufA, rowstart, elist, inv, aggbf, N);
  sage_gemm<<<gemmBlocks, 256, 0, stream>>>(aggbf, bufA, W3l, W3r, b3, out, nullptr, N, 0);
}

// Round 8
// 358.419 us; speedup vs baseline: 1.7753x; 1.1065x over previous
//
#include <hip/hip_runtime.h>

// GraphSAGE 3-layer, N=100k E=640k D=128.
// edge_index arrives as int32 (harness converts integer inputs to int32).
// CSR build: XCD-partitioned count -> hierarchical scan -> XCD-partitioned fill.
// Per layer: mean-aggregate (16 lanes/node, unroll-2 gather pipeline),
//   fused GEMM: out = agg@Wl^T + x@Wr^T + b  via mfma_f32_16x16x32_bf16.

typedef __attribute__((ext_vector_type(8))) short bf16x8;
typedef __attribute__((ext_vector_type(4))) float f32x4;
typedef __attribute__((ext_vector_type(4))) unsigned int u32x4;

__device__ __forceinline__ unsigned short f2bf(float f) {
  unsigned u = __float_as_uint(f);
  u += 0x7fffu + ((u >> 16) & 1u);   // RNE
  return (unsigned short)(u >> 16);
}

// ---------- fp32 -> bf16 convert, 8 elems/thread ----------
__global__ __launch_bounds__(256) void cvt_kernel(const float* __restrict__ in,
                                                  unsigned short* __restrict__ out, int n8) {
  int i = blockIdx.x * 256 + threadIdx.x;
  if (i >= n8) return;
  const float4* p = (const float4*)(in + (size_t)i * 8);
  float4 a = p[0], b = p[1];
  union { unsigned short s[8]; u32x4 u; } pk;
  pk.s[0] = f2bf(a.x); pk.s[1] = f2bf(a.y); pk.s[2] = f2bf(a.z); pk.s[3] = f2bf(a.w);
  pk.s[4] = f2bf(b.x); pk.s[5] = f2bf(b.y); pk.s[6] = f2bf(b.z); pk.s[7] = f2bf(b.w);
  *(u32x4*)(out + (size_t)i * 8) = pk.u;
}

// ---------- CSR build (XCD-partitioned by dst range) ----------
// Partition p = blockIdx & 7 handles dsts with (int)(d*pscale)==p; with the
// round-robin blockIdx->XCD mapping all atomics/writes for a dst range stay
// in one XCD's L2 (kills cross-XCD line ping-pong & 15x write amplification).
__global__ __launch_bounds__(256) void count_kernel(const int* __restrict__ dst,
                                                    int* __restrict__ cnt, int E, float pscale) {
  int p = blockIdx.x & 7;
  int blk = blockIdx.x >> 3;
  int stride = (gridDim.x >> 3) * 256;
  for (int e = blk * 256 + threadIdx.x; e < E; e += stride) {
    int d = dst[e];
    int pd = (int)((float)d * pscale);
    pd = pd > 7 ? 7 : pd;
    if (pd == p) atomicAdd(&cnt[d], 1);
  }
}

// 2048 counts per block -> blocksum[b]
__global__ __launch_bounds__(256) void partial_kernel(const int* __restrict__ cnt,
                                                      int* __restrict__ blocksum, int N) {
  __shared__ int red[256];
  int t = threadIdx.x;
  int idx = blockIdx.x * 2048 + t * 8;
  int s = 0;
  if (idx + 8 <= N) {
    int4 a = *(const int4*)(cnt + idx);
    int4 b = *(const int4*)(cnt + idx + 4);
    s = a.x + a.y + a.z + a.w + b.x + b.y + b.z + b.w;
  } else {
    for (int i = idx; i < N && i < idx + 8; ++i) s += cnt[i];
  }
  red[t] = s;
  __syncthreads();
  for (int off = 128; off > 0; off >>= 1) {
    if (t < off) red[t] += red[t + off];
    __syncthreads();
  }
  if (t == 0) blocksum[blockIdx.x] = red[0];
}

// single wave scans <=64 block partials -> exclusive blockoff[b]
__global__ __launch_bounds__(64) void scanmid_kernel(const int* __restrict__ blocksum,
                                                     int* __restrict__ blockoff, int nb) {
  int l = threadIdx.x;
  int own = (l < nb) ? blocksum[l] : 0;
  int v = own;
  for (int off = 1; off < 64; off <<= 1) {
    int u = __shfl_up(v, off);
    if (l >= off) v += u;
  }
  if (l < nb) blockoff[l] = v - own;
}

// local scan of 2048 counts + write rowstart/cursor/inv (init fused here)
__global__ __launch_bounds__(256) void final_kernel(const int* __restrict__ cnt,
                                                    const int* __restrict__ blockoff,
                                                    int* __restrict__ rowstart,
                                                    int* __restrict__ cursor,
                                                    float* __restrict__ inv, int N) {
  __shared__ int thr[256];
  int t = threadIdx.x;
  int idx = blockIdx.x * 2048 + t * 8;
  int c[8];
  int s = 0;
#pragma unroll
  for (int i = 0; i < 8; ++i) {
    int n = idx + i;
    c[i] = (n < N) ? cnt[n] : 0;
    s += c[i];
  }
  thr[t] = s;
  __syncthreads();
  for (int off = 1; off < 256; off <<= 1) {
    int u = (t >= off) ? thr[t - off] : 0;
    __syncthreads();
    thr[t] += u;
    __syncthreads();
  }
  int run = blockoff[blockIdx.x] + thr[t] - s;  // exclusive prefix for this thread
#pragma unroll
  for (int i = 0; i < 8; ++i) {
    int n = idx + i;
    if (n < N) {
      rowstart[n] = run;
      cursor[n] = run;
      inv[n] = 1.f / fmaxf((float)c[i], 1.f);
      run += c[i];
      if (n == N - 1) rowstart[N] = run;
    }
  }
}

__global__ __launch_bounds__(256) void fill_kernel(const int* __restrict__ src,
                                                   const int* __restrict__ dst,
                                                   int* __restrict__ cursor,
                                                   int* __restrict__ elist, int E, float pscale) {
  int p = blockIdx.x & 7;
  int blk = blockIdx.x >> 3;
  int stride = (gridDim.x >> 3) * 256;
  for (int e = blk * 256 + threadIdx.x; e < E; e += stride) {
    int d = dst[e];
    int s = src[e];
    int pd = (int)((float)d * pscale);
    pd = pd > 7 ? 7 : pd;
    if (pd == p) {
      int pos = atomicAdd(&cursor[d], 1);
      elist[pos] = s;
    }
  }
}

// ---------- mean aggregate: 16 lanes per node, unroll-2 gather pipeline ----------
// 4 nodes per wave -> 4 independent edge chains x 2 outstanding rows = MLP 8.
// Lane covers 8 cols via one dwordx4 (16 lanes x 16B = full 256B row).
__global__ __launch_bounds__(256) void aggregate_kernel(const unsigned short* __restrict__ xbf,
                                                        const int* __restrict__ rowstart,
                                                        const int* __restrict__ elist,
                                                        const float* __restrict__ inv,
                                                        unsigned short* __restrict__ aggbf, int N) {
  int gid = blockIdx.x * 256 + threadIdx.x;
  int node = gid >> 4;
  if (node >= N) return;
  int l16 = threadIdx.x & 15;

  int beg = rowstart[node], end = rowstart[node + 1];
  float acc[8];
#pragma unroll
  for (int j = 0; j < 8; ++j) acc[j] = 0.f;

  int e = beg;
  for (; e + 2 <= end; e += 2) {
    int s0 = elist[e];
    int s1 = elist[e + 1];
    u32x4 u0 = *(const u32x4*)(xbf + ((size_t)s0 << 7) + l16 * 8);
    u32x4 u1 = *(const u32x4*)(xbf + ((size_t)s1 << 7) + l16 * 8);
#pragma unroll
    for (int d = 0; d < 4; ++d) {
      acc[2 * d]     += __uint_as_float(u0[d] << 16);
      acc[2 * d + 1] += __uint_as_float(u0[d] & 0xffff0000u);
      acc[2 * d]     += __uint_as_float(u1[d] << 16);
      acc[2 * d + 1] += __uint_as_float(u1[d] & 0xffff0000u);
    }
  }
  if (e < end) {
    int s0 = elist[e];
    u32x4 u0 = *(const u32x4*)(xbf + ((size_t)s0 << 7) + l16 * 8);
#pragma unroll
    for (int d = 0; d < 4; ++d) {
      acc[2 * d]     += __uint_as_float(u0[d] << 16);
      acc[2 * d + 1] += __uint_as_float(u0[d] & 0xffff0000u);
    }
  }

  float iv = inv[node];
  union { unsigned short s[8]; u32x4 u; } pk;
#pragma unroll
  for (int j = 0; j < 8; ++j) pk.s[j] = f2bf(acc[j] * iv);
  *(u32x4*)(aggbf + ((size_t)node << 7) + l16 * 8) = pk.u;
}

// ---------- fused SAGE GEMM: out = Abf@Wl^T + Xbf@Wr^T + b ----------
// block = 256 thr (4 waves), tile = 256 rows x 128 cols; wave w owns 64 rows.
// Wl/Wr staged to LDS as bf16, 16B chunks XOR-swizzled by (o&15) to kill the
// o*256B-stride bank conflict on ds_read_b128.
__global__ __launch_bounds__(256, 2) void sage_gemm(
    const unsigned short* __restrict__ Abf, const unsigned short* __restrict__ Xbf,
    const float* __restrict__ Wl, const float* __restrict__ Wr, const float* __restrict__ bias,
    float* __restrict__ outf, unsigned short* __restrict__ outb, int N, int relu) {
  __shared__ __align__(16) unsigned short sW[2][128][128];  // 64 KB
  const int tid = threadIdx.x;
  for (int it = tid; it < 4096; it += 256) {
    int m = it >> 11;
    int o = (it >> 4) & 127;
    int ch = it & 15;
    const float* wsrc = (m ? Wr : Wl) + o * 128 + ch * 8;
    float4 f0 = *(const float4*)wsrc;
    float4 f1 = *(const float4*)(wsrc + 4);
    union { unsigned short s[8]; u32x4 u; } pk;
    pk.s[0] = f2bf(f0.x); pk.s[1] = f2bf(f0.y); pk.s[2] = f2bf(f0.z); pk.s[3] = f2bf(f0.w);
    pk.s[4] = f2bf(f1.x); pk.s[5] = f2bf(f1.y); pk.s[6] = f2bf(f1.z); pk.s[7] = f2bf(f1.w);
    *(u32x4*)&sW[m][o][(ch ^ (o & 15)) << 3] = pk.u;
  }
  __syncthreads();

  const int l = tid & 63;
  const int w = tid >> 6;
  const int l15 = l & 15;
  const int lg = l >> 4;
  const int row_base = blockIdx.x * 256 + w * 64;

  f32x4 acc[4][8];
#pragma unroll
  for (int rt = 0; rt < 4; ++rt)
#pragma unroll
    for (int ot = 0; ot < 8; ++ot) acc[rt][ot] = f32x4{0.f, 0.f, 0.f, 0.f};

  union frag { u32x4 u; bf16x8 v; };

  int rrow[4];
#pragma unroll
  for (int rt = 0; rt < 4; ++rt) {
    int r = row_base + rt * 16 + l15;
    rrow[rt] = (r < N) ? r : (N - 1);
  }

#pragma unroll
  for (int h = 0; h < 2; ++h) {
    const unsigned short* Asrc = h ? Xbf : Abf;
#pragma unroll
    for (int ks = 0; ks < 4; ++ks) {
      frag af[4];
#pragma unroll
      for (int rt = 0; rt < 4; ++rt)
        af[rt].u = *(const u32x4*)(Asrc + ((size_t)rrow[rt] << 7) + (ks * 32 + lg * 8));
      frag bq[8];
#pragma unroll
      for (int ot = 0; ot < 8; ++ot)
        bq[ot].u = *(const u32x4*)&sW[h][ot * 16 + l15][((((ks << 2) | lg) ^ l15)) << 3];
#pragma unroll
      for (int rt = 0; rt < 4; ++rt)
#pragma unroll
        for (int ot = 0; ot < 8; ++ot)
          acc[rt][ot] = __builtin_amdgcn_mfma_f32_16x16x32_bf16(af[rt].v, bq[ot].v, acc[rt][ot], 0, 0, 0);
    }
  }

  float bv[8];
#pragma unroll
  for (int ot = 0; ot < 8; ++ot) bv[ot] = bias[ot * 16 + l15];

#pragma unroll
  for (int rt = 0; rt < 4; ++rt) {
#pragma unroll
    for (int i = 0; i < 4; ++i) {
      int r = row_base + rt * 16 + lg * 4 + i;
      if (r < N) {
#pragma unroll
        for (int ot = 0; ot < 8; ++ot) {
          float v = acc[rt][ot][i] + bv[ot];
          if (relu) v = fmaxf(v, 0.f);
          size_t idx = ((size_t)r << 7) + ot * 16 + l15;
          if (outf) outf[idx] = v;
          else outb[idx] = f2bf(v);
        }
      }
    }
  }
}

extern "C" void kernel_launch(void* const* d_in, const int* in_sizes, int n_in,
                              void* d_out, int out_size, void* d_ws, size_t ws_size,
                              hipStream_t stream) {
  (void)n_in; (void)out_size; (void)ws_size;
  const float* x = (const float*)d_in[0];
  const int* ei = (const int*)d_in[1];     // int64 in reference -> int32 from harness
  const float* W1l = (const float*)d_in[2];
  const float* b1 = (const float*)d_in[3];
  const float* W1r = (const float*)d_in[4];
  const float* W2l = (const float*)d_in[5];
  const float* b2 = (const float*)d_in[6];
  const float* W2r = (const float*)d_in[7];
  const float* W3l = (const float*)d_in[8];
  const float* b3 = (const float*)d_in[9];
  const float* W3r = (const float*)d_in[10];
  float* out = (float*)d_out;

  const int N = in_sizes[0] / 128;
  const int E = in_sizes[1] / 2;
  const int* srcp = ei;
  const int* dstp = ei + E;
  const float pscale = 8.0f / (float)N;

  char* ws = (char*)d_ws;
  size_t off = 0;
  auto alloc = [&](size_t bytes) {
    void* p = ws + off;
    off = (off + bytes + 255) & ~(size_t)255;
    return p;
  };
  // Ping-pong node-feature buffers: bufA holds x (then layer-2 output), bufB holds layer-1 output.
  unsigned short* bufA = (unsigned short*)alloc((size_t)N * 128 * 2);
  unsigned short* bufB = (unsigned short*)alloc((size_t)N * 128 * 2);
  unsigned short* aggbf = (unsigned short*)alloc((size_t)N * 128 * 2);
  int* cnt = (int*)alloc((size_t)N * 4);
  int* rowstart = (int*)alloc((size_t)(N + 1) * 4);
  int* cursor = (int*)alloc((size_t)N * 4);
  float* inv = (float*)alloc((size_t)N * 4);
  int* elist = (int*)alloc((size_t)E * 4);
  int* blocksum = (int*)alloc(64 * 4);
  int* blockoff = (int*)alloc(64 * 4);

  const int nb = (N + 2047) / 2048;  // 49 for N=100k (<=64 by construction here)

  hipMemsetAsync(cnt, 0, (size_t)N * 4, stream);
  cvt_kernel<<<(N * 128 / 8 + 255) / 256, 256, 0, stream>>>(x, bufA, N * 128 / 8);
  count_kernel<<<1024, 256, 0, stream>>>(dstp, cnt, E, pscale);
  partial_kernel<<<nb, 256, 0, stream>>>(cnt, blocksum, N);
  scanmid_kernel<<<1, 64, 0, stream>>>(blocksum, blockoff, nb);
  final_kernel<<<nb, 256, 0, stream>>>(cnt, blockoff, rowstart, cursor, inv, N);
  fill_kernel<<<1024, 256, 0, stream>>>(srcp, dstp, cursor, elist, E, pscale);

  int aggBlocks = (N * 16 + 255) / 256;
  int gemmBlocks = (N + 255) / 256;

  // layer 1: bufA(x) -> bufB (relu)
  aggregate_kernel<<<aggBlocks, 256, 0, stream>>>(bufA, rowstart, elist, inv, aggbf, N);
  sage_gemm<<<gemmBlocks, 256, 0, stream>>>(aggbf, bufA, W1l, W1r, b1, nullptr, bufB, N, 1);
  // layer 2: bufB -> bufA (relu; x dead, safe to overwrite)
  aggregate_kernel<<<aggBlocks, 256, 0, stream>>>(bufB, rowstart, elist, inv, aggbf, N);
  sage_gemm<<<gemmBlocks, 256, 0, stream>>>(aggbf, bufB, W2l, W2r, b2, nullptr, bufA, N, 1);
  // layer 3: bufA -> out (no relu, fp32)
  aggregate_kernel<<<aggBlocks, 256, 0, stream>>>(bufA, rowstart, elist, inv, aggbf, N);
  sage_gemm<<<gemmBlocks, 256, 0, stream>>>(aggbf, bufA, W3l, W3r, b3, out, nullptr, N, 0);
}